// Round 10
// baseline (358.367 us; speedup 1.0000x reference)
//
#include <hip/hip_runtime.h>
#include <hip/hip_bf16.h>

typedef __bf16    bf16x8  __attribute__((ext_vector_type(8)));
typedef __bf16    bf16x4  __attribute__((ext_vector_type(4)));
typedef _Float16  half8   __attribute__((ext_vector_type(8)));
typedef _Float16  half4   __attribute__((ext_vector_type(4)));
typedef _Float16  half2   __attribute__((ext_vector_type(2)));
typedef float     floatx4 __attribute__((ext_vector_type(4)));

constexpr int Bc  = 2;
constexpr int Hc  = 16;
constexpr int Lc  = 2048;
constexpr int Dc  = 64;
constexpr int BHn = Bc * Hc;     // 32
constexpr int BM  = 128;         // query rows per block (2 strips of 16 per wave)
constexpr int BN  = 128;         // keys per tile
constexpr int NQT = Lc / BM;     // 16 query tiles
constexpr int LDK = 72;          // Ks padded stride (bf16 elems)
constexpr int LDV = 136;         // VT padded stride (fp16 elems)

static __device__ __forceinline__ half2 pack_f16(float a, float b) {
    return __builtin_bit_cast(half2, __builtin_amdgcn_cvt_pkrtz(a, b));
}

// ---- fused pre-pass: K fp32->bf16, V fp32 -> fp16 transposed+key-permuted; zero tickets ----
__global__ void prep(const float* __restrict__ kp, const float* __restrict__ vp,
                     __bf16* __restrict__ k16, _Float16* __restrict__ v16,
                     int* __restrict__ ctrflag) {
    const int bid = blockIdx.x, tid = threadIdx.x;
    if (bid == 0 && tid < 256) {            // zero 512 ctr + 512 flag ints
        #pragma unroll
        for (int r = 0; r < 4; ++r) ctrflag[tid + 256 * r] = 0;
    }
    if (bid < 1024) {
        const size_t base = (size_t)bid * 4096 + tid * 4;
        #pragma unroll
        for (int rep = 0; rep < 4; ++rep) {
            const size_t i = base + rep * 1024;
            floatx4 v = *(const floatx4*)(kp + i);
            bf16x4 b;
            b[0] = (__bf16)v[0]; b[1] = (__bf16)v[1]; b[2] = (__bf16)v[2]; b[3] = (__bf16)v[3];
            *(bf16x4*)(k16 + i) = b;
        }
    } else {
        const int vb  = bid - 1024;
        const int bh  = vb >> 5, kt = vb & 31;
        const int key = kt * 64 + (tid & 63);
        const int k5  = key & 31;
        const int pcol = (key & ~31) | (((k5 >> 2) & 3) * 8 + ((k5 >> 4) & 1) * 4 + (k5 & 3));
        const int d0  = (tid >> 6) * 16;
        const float* src = vp + ((size_t)bh * Lc + key) * Dc;
        _Float16*    dst = v16 + (size_t)bh * Dc * Lc + pcol;
        #pragma unroll
        for (int i = 0; i < 16; ++i) {
            const int d = d0 + i;
            dst[(size_t)d * Lc] = (_Float16)src[d];
        }
    }
}

// ---- main kernel: 1024 blocks (KV-split halves), 4 blocks/CU, atomic last-writer combine ----
__global__ __launch_bounds__(256, 4)
void taylor_attn(const float* __restrict__ qp, const __bf16* __restrict__ k16,
                 const _Float16* __restrict__ v16, float* __restrict__ op,
                 float* __restrict__ Oa, float* __restrict__ za,
                 int* __restrict__ ctr, int* __restrict__ flag)
{
    __shared__ __bf16   Ks[BN * LDK];   // 18432 B; also used for Q staging (128 x 72)
    __shared__ _Float16 VT[Dc * LDV];   // 17408 B: V^T tile [d][pcol 0..127]
    __shared__ int      s_old;

    const int tid  = threadIdx.x;
    const int wv   = tid >> 6;
    const int lane = tid & 63;
    const int lm   = lane & 15;
    const int quad = lane >> 4;

    // length-sorted dispatch: round r (heaviest first), odd rounds reversed for balance
    const int r    = (int)(blockIdx.x >> 8);
    const int s    = (int)((blockIdx.x >> 5) & 7);
    const int bh   = (int)(blockIdx.x & 31);
    const int seff = (r & 1) ? (7 - s) : s;
    const int qi   = (15 - 4 * r) - (seff >> 1);
    const int half = seff & 1;
    const int q0   = qi * BM;
    const int nlo  = (qi + 2) >> 1;                   // lower-half tile count
    const int j0   = half ? nlo : 0;
    const int jend = half ? (qi + 1) : nlo;           // may equal j0 (qi=0 hi: empty)

    const float*    qbase = qp  + ((size_t)bh * Lc + q0) * Dc;
    const __bf16*   kj    = k16 + (size_t)bh * Lc * Dc + (size_t)j0 * BN * Dc;
    const _Float16* vj    = v16 + (size_t)bh * Dc * Lc + (size_t)j0 * BN;

    // ---- prefetch tile j0 into registers (in flight during Q staging) ----
    bf16x8 kr[4]; half8 vr[4];
    #pragma unroll
    for (int rep = 0; rep < 4; ++rep)
        kr[rep] = *(const bf16x8*)(kj + 8 * (tid + 256 * rep));
    #pragma unroll
    for (int rep = 0; rep < 4; ++rep) {
        const int g = tid + 256 * rep;                // granule: row=d (g>>4), col=(g&15)*8
        vr[rep] = *(const half8*)(vj + (size_t)(g >> 4) * Lc + (g & 15) * 8);
    }

    // ---- stage Q (fp32 -> bf16) into Ks area, extract per-strip B-frags ----
    {
        const int r0 = tid >> 4, c4 = tid & 15;
        #pragma unroll
        for (int rep = 0; rep < 8; ++rep) {
            const int row = r0 + rep * 16;
            floatx4 v = *(const floatx4*)(qbase + row * Dc + c4 * 4);
            bf16x4 b;
            b[0] = (__bf16)v[0]; b[1] = (__bf16)v[1]; b[2] = (__bf16)v[2]; b[3] = (__bf16)v[3];
            *(bf16x4*)&Ks[row * LDK + c4 * 4] = b;
        }
    }
    __syncthreads();
    bf16x8 qa[2][2];   // [strip][kf]; B-frag: n=lm (qrow), k=kf*32+quad*8+j
    #pragma unroll
    for (int st = 0; st < 2; ++st)
        #pragma unroll
        for (int kf = 0; kf < 2; ++kf)
            qa[st][kf] = *(const bf16x8*)&Ks[(32 * wv + 16 * st + lm) * LDK + kf * 32 + quad * 8];
    __syncthreads();

    floatx4 oacc[2][4] = {};     // O^T accum: [strip][d-block]; col=qrow=lm, row=d=quad*4+r
    floatx4 zacc[2]    = {};     // z via ones-MFMA: every element = z[qrow=lm]

    const half8 ones = {(_Float16)1.f, (_Float16)1.f, (_Float16)1.f, (_Float16)1.f,
                        (_Float16)1.f, (_Float16)1.f, (_Float16)1.f, (_Float16)1.f};
    const half2 c8  = {(_Float16)0.125f, (_Float16)0.125f};
    const half2 c1  = {(_Float16)1.f,    (_Float16)1.f};
    const half2 ch  = {(_Float16)0.5f,   (_Float16)0.5f};

    for (int j = j0; j < jend; ++j) {
        // ---- write the prefetched tile into LDS ----
        #pragma unroll
        for (int rep = 0; rep < 4; ++rep) {
            const int c = tid + 256 * rep;
            *(bf16x8*)&Ks[(c >> 3) * LDK + (c & 7) * 8] = kr[rep];
        }
        #pragma unroll
        for (int rep = 0; rep < 4; ++rep) {
            const int g = tid + 256 * rep;
            *(half8*)&VT[(g >> 4) * LDV + (g & 15) * 8] = vr[rep];
        }
        __syncthreads();

        // ---- issue next tile's loads: full compute phase to land ----
        if (j + 1 < jend) {
            kj += BN * Dc;
            vj += BN;
            #pragma unroll
            for (int rep = 0; rep < 4; ++rep)
                kr[rep] = *(const bf16x8*)(kj + 8 * (tid + 256 * rep));
            #pragma unroll
            for (int rep = 0; rep < 4; ++rep) {
                const int g = tid + 256 * rep;
                vr[rep] = *(const half8*)(vj + (size_t)(g >> 4) * Lc + (g & 15) * 8);
            }
        }

        const bool nm = (j == qi);                   // only the global diagonal tile masks
        #pragma unroll
        for (int kh = 0; kh < 2; ++kh) {             // two key-halves of 64
            floatx4 sacc[2][4] = {};
            #pragma unroll
            for (int kb4 = 0; kb4 < 4; ++kb4) {
                const int kb = 4 * kh + kb4;
                #pragma unroll
                for (int kf = 0; kf < 2; ++kf) {
                    bf16x8 ka = *(const bf16x8*)&Ks[(16 * kb + lm) * LDK + kf * 32 + quad * 8];
                    sacc[0][kb4] = __builtin_amdgcn_mfma_f32_16x16x32_bf16(ka, qa[0][kf], sacc[0][kb4], 0, 0, 0);
                    sacc[1][kb4] = __builtin_amdgcn_mfma_f32_16x16x32_bf16(ka, qa[1][kf], sacc[1][kb4], 0, 0, 0);
                }
            }

            half8 wf[2][2];
            #pragma unroll
            for (int st = 0; st < 2; ++st) {
                const int strip_lo = q0 + 32 * wv + 16 * st;
                const int thr = strip_lo + lm - j * BN;
                half2 wh[4][2];
                #pragma unroll
                for (int kb4 = 0; kb4 < 4; ++kb4) {
                    half2 s01 = pack_f16(sacc[st][kb4][0], sacc[st][kb4][1]);
                    half2 s23 = pack_f16(sacc[st][kb4][2], sacc[st][kb4][3]);
                    half2 a01 = s01 * c8 + c1;            // fuses to v_pk_fma_f16
                    half2 a23 = s23 * c8 + c1;
                    half2 w01 = a01 * (a01 * ch) + ch;    // 0.5*a^2 + 0.5
                    half2 w23 = a23 * (a23 * ch) + ch;
                    if (nm) {
                        const int i0 = 16 * (4 * kh + kb4) + 4 * quad;
                        w01[0] = (i0 + 0 <= thr) ? w01[0] : (_Float16)0.f;
                        w01[1] = (i0 + 1 <= thr) ? w01[1] : (_Float16)0.f;
                        w23[0] = (i0 + 2 <= thr) ? w23[0] : (_Float16)0.f;
                        w23[1] = (i0 + 3 <= thr) ? w23[1] : (_Float16)0.f;
                    }
                    wh[kb4][0] = w01;
                    wh[kb4][1] = w23;
                }
                #pragma unroll
                for (int g2 = 0; g2 < 2; ++g2) {
                    half4 lo = __builtin_shufflevector(wh[2 * g2][0],     wh[2 * g2][1],     0, 1, 2, 3);
                    half4 hi = __builtin_shufflevector(wh[2 * g2 + 1][0], wh[2 * g2 + 1][1], 0, 1, 2, 3);
                    wf[st][g2] = __builtin_shufflevector(lo, hi, 0, 1, 2, 3, 4, 5, 6, 7);
                }
            }

            #pragma unroll
            for (int db = 0; db < 4; ++db)
                #pragma unroll
                for (int g2 = 0; g2 < 2; ++g2) {
                    const int grp = 2 * kh + g2;
                    half8 va = *(const half8*)&VT[(16 * db + lm) * LDV + 32 * grp + 8 * quad];
                    oacc[0][db] = __builtin_amdgcn_mfma_f32_16x16x32_f16(va, wf[0][g2], oacc[0][db], 0, 0, 0);
                    oacc[1][db] = __builtin_amdgcn_mfma_f32_16x16x32_f16(va, wf[1][g2], oacc[1][db], 0, 0, 0);
                }
            #pragma unroll
            for (int g2 = 0; g2 < 2; ++g2) {
                zacc[0] = __builtin_amdgcn_mfma_f32_16x16x32_f16(ones, wf[0][g2], zacc[0], 0, 0, 0);
                zacc[1] = __builtin_amdgcn_mfma_f32_16x16x32_f16(ones, wf[1][g2], zacc[1], 0, 0, 0);
            }
        }
        __syncthreads();   // all waves done reading Ks/VT before next iteration's write
    }

    // ---- combine protocol: first finisher publishes partials; second combines + stores ----
    const int pid = (qi << 5) | bh;
    float* Opart = Oa + (size_t)pid * (256 * 32);
    float* zpart = za + (size_t)pid * 128;

    if (tid == 0) s_old = atomicAdd(&ctr[pid], 1);
    __syncthreads();

    if (s_old == 0) {
        // publish unnormalized partials (coalesced: thread tid -> 32 consecutive floats)
        float* dst = Opart + tid * 32;
        #pragma unroll
        for (int st = 0; st < 2; ++st)
            #pragma unroll
            for (int db = 0; db < 4; ++db)
                *(floatx4*)(dst + (st * 4 + db) * 4) = oacc[st][db];
        if (quad == 0) {
            zpart[32 * wv + lm]      = zacc[0][0];
            zpart[32 * wv + 16 + lm] = zacc[1][0];
        }
        __threadfence();
        __syncthreads();
        if (tid == 0)
            __hip_atomic_store(&flag[pid], 1, __ATOMIC_RELEASE, __HIP_MEMORY_SCOPE_AGENT);
        return;
    }

    // second finisher: partner already past its atomic; it only stores + exits -> no deadlock
    if (tid == 0) {
        while (__hip_atomic_load(&flag[pid], __ATOMIC_ACQUIRE, __HIP_MEMORY_SCOPE_AGENT) == 0) {}
    }
    __syncthreads();
    __threadfence();

    const float* src = Opart + tid * 32;
    #pragma unroll
    for (int st = 0; st < 2; ++st)
        #pragma unroll
        for (int db = 0; db < 4; ++db)
            oacc[st][db] += *(const floatx4*)(src + (st * 4 + db) * 4);
    const float zo[2] = {zpart[32 * wv + lm], zpart[32 * wv + 16 + lm]};

    #pragma unroll
    for (int st = 0; st < 2; ++st) {
        const float inv = 1.0f / (zacc[st][0] + zo[st] + 1e-6f);
        const int qrow = q0 + 32 * wv + 16 * st + lm;
        float* orow = op + ((size_t)bh * Lc + qrow) * Dc;
        #pragma unroll
        for (int db = 0; db < 4; ++db)
            #pragma unroll
            for (int rr = 0; rr < 4; ++rr)
                orow[16 * db + 4 * quad + rr] = oacc[st][db][rr] * inv;
    }
}

extern "C" void kernel_launch(void* const* d_in, const int* in_sizes, int n_in,
                              void* d_out, int out_size, void* d_ws, size_t ws_size,
                              hipStream_t stream) {
    const float* q = (const float*)d_in[0];
    const float* k = (const float*)d_in[1];
    const float* v = (const float*)d_in[2];
    float* o = (float*)d_out;

    char* ws = (char*)d_ws;
    constexpr size_t SZ_KV = (size_t)BHn * Lc * Dc * 2;        // 8 MB each
    constexpr size_t SZ_OA = (size_t)512 * 256 * 32 * 4;       // 16 MB
    constexpr size_t SZ_ZA = (size_t)512 * 128 * 4;            // 256 KB
    __bf16*   k16 = (__bf16*)ws;
    _Float16* v16 = (_Float16*)(ws + SZ_KV);
    float*    Oa  = (float*)(ws + 2 * SZ_KV);
    float*    za  = (float*)(ws + 2 * SZ_KV + SZ_OA);
    int*      ctf = (int*)(ws + 2 * SZ_KV + SZ_OA + SZ_ZA);    // ctr[512] ++ flag[512]

    prep<<<dim3(2048), dim3(256), 0, stream>>>(k, v, k16, v16, ctf);
    taylor_attn<<<dim3(1024), dim3(256), 0, stream>>>(q, k16, v16, o, Oa, za, ctf, ctf + 512);
}